// Round 4
// baseline (164.501 us; speedup 1.0000x reference)
//
#include <hip/hip_runtime.h>

// K=128 users, M=1024, N=C=128.
// k1 (134 MB streamed, read-bound): h[k,m] = h_d[k,m] + sum_n A[k,m,n]*v[n]
//     R4: 16-lane reduction done entirely with DPP (quad_perm / row mirrors)
//     in the VALU pipe -- no ds_swizzle, no lgkmcnt stalls against the loads.
// k2: partial g = h @ W over 8 m-slices, float4 W loads
// k3 (tiny): reduce partials -> mag -> SINR -> atomicAdd

#define KM_ROWS (128 * 1024)

__device__ __forceinline__ float dot4(float4 a, float4 b) {
    return a.x*b.x + a.y*b.y + a.z*b.z + a.w*b.w;
}

// x += value from lane given by DPP control (within each row of 16 lanes)
template<int CTRL>
__device__ __forceinline__ float dpp_xadd(float x) {
    union { float f; int i; } u, v;
    u.f = x;
    v.i = __builtin_amdgcn_mov_dpp(u.i, CTRL, 0xf, 0xf, false);
    return x + v.f;
}

// full sum across each 16-lane group, result in all 16 lanes
__device__ __forceinline__ float sum16(float x) {
    x = dpp_xadd<0xB1>(x);   // quad_perm [1,0,3,2]  : xor 1
    x = dpp_xadd<0x4E>(x);   // quad_perm [2,3,0,1]  : xor 2
    x = dpp_xadd<0x141>(x);  // row_half_mirror      : folds quads 0<->1, 2<->3
    x = dpp_xadd<0x140>(x);  // row_mirror           : folds halves
    return x;
}

__global__ __launch_bounds__(256) void compute_h_kernel(
    const float* __restrict__ A_real,
    const float* __restrict__ A_imag,
    const float* __restrict__ W_v,       // row 0 = v (256 floats: v_re | v_im)
    const float* __restrict__ h_d_real,
    const float* __restrict__ h_d_imag,
    float* __restrict__ h_re,
    float* __restrict__ h_im)
{
    const int lane = threadIdx.x & 63;
    const int sub  = lane & 15;          // chunk within row (16 lanes/row)
    const int rsub = lane >> 4;          // row within quad (0..3)
    const int wid  = blockIdx.x * 4 + (threadIdx.x >> 6);
    const int nw   = gridDim.x * 4;

    // v chunks (row 0 of W_v): re = float4[0..31], im = [32..63]
    const float4 vr0 = ((const float4*)W_v)[sub];
    const float4 vr1 = ((const float4*)W_v)[sub + 16];
    const float4 vi0 = ((const float4*)W_v)[32 + sub];
    const float4 vi1 = ((const float4*)W_v)[48 + sub];

    // each wave-iteration covers 8 consecutive rows (two quads)
    for (int base = wid; base < KM_ROWS / 8; base += nw) {
        const int r0 = base * 8 + rsub;
        const int r1 = r0 + 4;
        const float4* Ar0 = (const float4*)(A_real + (size_t)r0 * 128);
        const float4* Ai0 = (const float4*)(A_imag + (size_t)r0 * 128);
        const float4* Ar1 = (const float4*)(A_real + (size_t)r1 * 128);
        const float4* Ai1 = (const float4*)(A_imag + (size_t)r1 * 128);

        const float4 a0 = Ar0[sub];
        const float4 a1 = Ar0[sub + 16];
        const float4 b0 = Ai0[sub];
        const float4 b1 = Ai0[sub + 16];
        const float4 c0 = Ar1[sub];
        const float4 c1 = Ar1[sub + 16];
        const float4 d0 = Ai1[sub];
        const float4 d1 = Ai1[sub + 16];

        const float hdr0 = h_d_real[r0], hdi0 = h_d_imag[r0];
        const float hdr1 = h_d_real[r1], hdi1 = h_d_imag[r1];

        float p_re = dot4(a0, vr0) + dot4(a1, vr1) - dot4(b0, vi0) - dot4(b1, vi1);
        float p_im = dot4(b0, vr0) + dot4(b1, vr1) + dot4(a0, vi0) + dot4(a1, vi1);
        float q_re = dot4(c0, vr0) + dot4(c1, vr1) - dot4(d0, vi0) - dot4(d1, vi1);
        float q_im = dot4(d0, vr0) + dot4(d1, vr1) + dot4(c0, vi0) + dot4(c1, vi1);

        // 16-lane sums, all in the VALU pipe (DPP), no LDS traffic
        p_re = sum16(p_re);
        p_im = sum16(p_im);
        q_re = sum16(q_re);
        q_im = sum16(q_im);

        if (sub == 0) {
            h_re[r0] = hdr0 + p_re;
            h_im[r0] = hdi0 + p_im;
            h_re[r1] = hdr1 + q_re;
            h_im[r1] = hdi1 + q_im;
        }
    }
}

__global__ __launch_bounds__(256) void gemm_partial_kernel(
    const float* __restrict__ h_re,
    const float* __restrict__ h_im,
    const float* __restrict__ W_v,       // rows 1.. = W (1024 x 256)
    float* __restrict__ part_re,         // [8][128][128] = [slice][k][c]
    float* __restrict__ part_im)
{
    const int k     = blockIdx.x >> 3;   // 0..127
    const int slice = blockIdx.x & 7;    // 0..7 (m-slice of 128)
    const int t  = threadIdx.x;          // 0..255
    const int c4 = t & 31;               // column group (4 cols each)
    const int seg = t >> 5;              // m-subrange (16 rows each)

    __shared__ float sh_re[128], sh_im[128];
    if (t < 128) {
        sh_re[t] = h_re[k * 1024 + slice * 128 + t];
        sh_im[t] = h_im[k * 1024 + slice * 128 + t];
    }
    __syncthreads();

    const float* Wb = W_v + 256 + (size_t)(slice * 128) * 256;
    float4 gre = {0.f, 0.f, 0.f, 0.f};
    float4 gim = {0.f, 0.f, 0.f, 0.f};
    const int m0 = seg * 16;
    #pragma unroll 4
    for (int m = m0; m < m0 + 16; ++m) {
        const float4* Wr4 = (const float4*)(Wb + m * 256);
        float4 wr = Wr4[c4];
        float4 wi = Wr4[c4 + 32];
        float hr = sh_re[m];
        float hi = sh_im[m];
        gre.x = fmaf(hr, wr.x, gre.x); gre.x = fmaf(-hi, wi.x, gre.x);
        gre.y = fmaf(hr, wr.y, gre.y); gre.y = fmaf(-hi, wi.y, gre.y);
        gre.z = fmaf(hr, wr.z, gre.z); gre.z = fmaf(-hi, wi.z, gre.z);
        gre.w = fmaf(hr, wr.w, gre.w); gre.w = fmaf(-hi, wi.w, gre.w);
        gim.x = fmaf(hr, wi.x, gim.x); gim.x = fmaf(hi, wr.x, gim.x);
        gim.y = fmaf(hr, wi.y, gim.y); gim.y = fmaf(hi, wr.y, gim.y);
        gim.z = fmaf(hr, wi.z, gim.z); gim.z = fmaf(hi, wr.z, gim.z);
        gim.w = fmaf(hr, wi.w, gim.w); gim.w = fmaf(hi, wr.w, gim.w);
    }

    __shared__ float4 s_re[256], s_im[256];
    s_re[t] = gre; s_im[t] = gim;
    __syncthreads();
    if (t < 32) {
        float4 r = s_re[t], i = s_im[t];
        #pragma unroll
        for (int s = 1; s < 8; ++s) {
            float4 rr = s_re[s * 32 + t], ii = s_im[s * 32 + t];
            r.x += rr.x; r.y += rr.y; r.z += rr.z; r.w += rr.w;
            i.x += ii.x; i.y += ii.y; i.z += ii.z; i.w += ii.w;
        }
        float4* pr = (float4*)(part_re + (size_t)(slice * 128 + k) * 128);
        float4* pi = (float4*)(part_im + (size_t)(slice * 128 + k) * 128);
        pr[t] = r;
        pi[t] = i;
    }
}

__global__ __launch_bounds__(128) void rate_kernel(
    const float* __restrict__ part_re,
    const float* __restrict__ part_im,
    float* __restrict__ out)
{
    const int k = blockIdx.x;    // 0..127
    const int c = threadIdx.x;   // 0..127

    float gr = 0.f, gi = 0.f;
    #pragma unroll
    for (int s = 0; s < 8; ++s) {
        gr += part_re[(s * 128 + k) * 128 + c];
        gi += part_im[(s * 128 + k) * 128 + c];
    }
    float mag = sqrtf(gr * gr + gi * gi);

    __shared__ float s_sig;
    __shared__ float s_w[2];
    if (c == k) s_sig = mag;

    float v = mag;
    #pragma unroll
    for (int off = 32; off > 0; off >>= 1) v += __shfl_xor(v, off);
    if ((c & 63) == 0) s_w[c >> 6] = v;
    __syncthreads();

    if (c == 0) {
        float total  = s_w[0] + s_w[1];
        float interf = total - s_sig;
        float R      = s_sig / (interf + 1e-11f);   // N0 = 10^(-80/10)/1000
        atomicAdd(out, -R * 1e6f);
    }
}

extern "C" void kernel_launch(void* const* d_in, const int* in_sizes, int n_in,
                              void* d_out, int out_size, void* d_ws, size_t ws_size,
                              hipStream_t stream) {
    const float* W_v      = (const float*)d_in[0];
    const float* A_real   = (const float*)d_in[1];
    const float* A_imag   = (const float*)d_in[2];
    const float* h_d_real = (const float*)d_in[3];
    const float* h_d_imag = (const float*)d_in[4];
    float* out  = (float*)d_out;

    float* h_re    = (float*)d_ws;          // 131072 floats
    float* h_im    = h_re + KM_ROWS;        // 131072 floats
    float* part_re = h_im + KM_ROWS;        // 8*128*128 = 131072 floats
    float* part_im = part_re + 8 * 128 * 128;

    hipMemsetAsync(d_out, 0, sizeof(float), stream);

    compute_h_kernel<<<2048, 256, 0, stream>>>(A_real, A_imag, W_v,
                                               h_d_real, h_d_imag, h_re, h_im);
    gemm_partial_kernel<<<1024, 256, 0, stream>>>(h_re, h_im, W_v, part_re, part_im);
    rate_kernel<<<128, 128, 0, stream>>>(part_re, part_im, out);
}

// Round 5
// 159.559 us; speedup vs baseline: 1.0310x; 1.0310x over previous
//
#include <hip/hip_runtime.h>

// K=128 users, M=1024, N=C=128.
// k1 (134 MB streamed, latency/MSHR-bound): h = h_d + A·v (complex)
//     R5: non-temporal loads for A (skip L1 allocation -- A is single-use;
//     theory: per-CU L1 miss-buffer cap throttles streaming reads to ~3 TB/s)
// k2: partial g = h @ W over 8 m-slices, float4 W loads
// k3 (tiny): reduce partials -> mag -> SINR -> atomicAdd

#define KM_ROWS (128 * 1024)

typedef float vf4 __attribute__((ext_vector_type(4)));

__device__ __forceinline__ float dot4v(vf4 a, const float4& b) {
    return a.x*b.x + a.y*b.y + a.z*b.z + a.w*b.w;
}

template<int CTRL>
__device__ __forceinline__ float dpp_xadd(float x) {
    union { float f; int i; } u, v;
    u.f = x;
    v.i = __builtin_amdgcn_mov_dpp(u.i, CTRL, 0xf, 0xf, false);
    return x + v.f;
}

__device__ __forceinline__ float sum16(float x) {
    x = dpp_xadd<0xB1>(x);   // quad_perm xor1
    x = dpp_xadd<0x4E>(x);   // quad_perm xor2
    x = dpp_xadd<0x141>(x);  // row_half_mirror
    x = dpp_xadd<0x140>(x);  // row_mirror
    return x;
}

__global__ __launch_bounds__(256) void compute_h_kernel(
    const float* __restrict__ A_real,
    const float* __restrict__ A_imag,
    const float* __restrict__ W_v,       // row 0 = v (256 floats: v_re | v_im)
    const float* __restrict__ h_d_real,
    const float* __restrict__ h_d_imag,
    float* __restrict__ h_re,
    float* __restrict__ h_im)
{
    const int lane = threadIdx.x & 63;
    const int sub  = lane & 15;          // chunk within row (16 lanes/row)
    const int rsub = lane >> 4;          // row within quad (0..3)
    const int wid  = blockIdx.x * 4 + (threadIdx.x >> 6);
    const int nw   = gridDim.x * 4;

    const float4 vr0 = ((const float4*)W_v)[sub];
    const float4 vr1 = ((const float4*)W_v)[sub + 16];
    const float4 vi0 = ((const float4*)W_v)[32 + sub];
    const float4 vi1 = ((const float4*)W_v)[48 + sub];

    for (int base = wid; base < KM_ROWS / 8; base += nw) {
        const int r0 = base * 8 + rsub;
        const int r1 = r0 + 4;
        const vf4* Ar0 = (const vf4*)(A_real + (size_t)r0 * 128);
        const vf4* Ai0 = (const vf4*)(A_imag + (size_t)r0 * 128);
        const vf4* Ar1 = (const vf4*)(A_real + (size_t)r1 * 128);
        const vf4* Ai1 = (const vf4*)(A_imag + (size_t)r1 * 128);

        // non-temporal: skip L1 allocation for single-use stream
        const vf4 a0 = __builtin_nontemporal_load(Ar0 + sub);
        const vf4 a1 = __builtin_nontemporal_load(Ar0 + sub + 16);
        const vf4 b0 = __builtin_nontemporal_load(Ai0 + sub);
        const vf4 b1 = __builtin_nontemporal_load(Ai0 + sub + 16);
        const vf4 c0 = __builtin_nontemporal_load(Ar1 + sub);
        const vf4 c1 = __builtin_nontemporal_load(Ar1 + sub + 16);
        const vf4 d0 = __builtin_nontemporal_load(Ai1 + sub);
        const vf4 d1 = __builtin_nontemporal_load(Ai1 + sub + 16);

        const float hdr0 = h_d_real[r0], hdi0 = h_d_imag[r0];
        const float hdr1 = h_d_real[r1], hdi1 = h_d_imag[r1];

        float p_re = dot4v(a0, vr0) + dot4v(a1, vr1) - dot4v(b0, vi0) - dot4v(b1, vi1);
        float p_im = dot4v(b0, vr0) + dot4v(b1, vr1) + dot4v(a0, vi0) + dot4v(a1, vi1);
        float q_re = dot4v(c0, vr0) + dot4v(c1, vr1) - dot4v(d0, vi0) - dot4v(d1, vi1);
        float q_im = dot4v(d0, vr0) + dot4v(d1, vr1) + dot4v(c0, vi0) + dot4v(c1, vi1);

        p_re = sum16(p_re);
        p_im = sum16(p_im);
        q_re = sum16(q_re);
        q_im = sum16(q_im);

        if (sub == 0) {
            h_re[r0] = hdr0 + p_re;
            h_im[r0] = hdi0 + p_im;
            h_re[r1] = hdr1 + q_re;
            h_im[r1] = hdi1 + q_im;
        }
    }
}

__global__ __launch_bounds__(256) void gemm_partial_kernel(
    const float* __restrict__ h_re,
    const float* __restrict__ h_im,
    const float* __restrict__ W_v,       // rows 1.. = W (1024 x 256)
    float* __restrict__ part_re,         // [8][128][128] = [slice][k][c]
    float* __restrict__ part_im)
{
    const int k     = blockIdx.x >> 3;   // 0..127
    const int slice = blockIdx.x & 7;    // 0..7 (m-slice of 128)
    const int t  = threadIdx.x;          // 0..255
    const int c4 = t & 31;               // column group (4 cols each)
    const int seg = t >> 5;              // m-subrange (16 rows each)

    __shared__ float sh_re[128], sh_im[128];
    if (t < 128) {
        sh_re[t] = h_re[k * 1024 + slice * 128 + t];
        sh_im[t] = h_im[k * 1024 + slice * 128 + t];
    }
    __syncthreads();

    const float* Wb = W_v + 256 + (size_t)(slice * 128) * 256;
    float4 gre = {0.f, 0.f, 0.f, 0.f};
    float4 gim = {0.f, 0.f, 0.f, 0.f};
    const int m0 = seg * 16;
    #pragma unroll 4
    for (int m = m0; m < m0 + 16; ++m) {
        const float4* Wr4 = (const float4*)(Wb + m * 256);
        float4 wr = Wr4[c4];
        float4 wi = Wr4[c4 + 32];
        float hr = sh_re[m];
        float hi = sh_im[m];
        gre.x = fmaf(hr, wr.x, gre.x); gre.x = fmaf(-hi, wi.x, gre.x);
        gre.y = fmaf(hr, wr.y, gre.y); gre.y = fmaf(-hi, wi.y, gre.y);
        gre.z = fmaf(hr, wr.z, gre.z); gre.z = fmaf(-hi, wi.z, gre.z);
        gre.w = fmaf(hr, wr.w, gre.w); gre.w = fmaf(-hi, wi.w, gre.w);
        gim.x = fmaf(hr, wi.x, gim.x); gim.x = fmaf(hi, wr.x, gim.x);
        gim.y = fmaf(hr, wi.y, gim.y); gim.y = fmaf(hi, wr.y, gim.y);
        gim.z = fmaf(hr, wi.z, gim.z); gim.z = fmaf(hi, wr.z, gim.z);
        gim.w = fmaf(hr, wi.w, gim.w); gim.w = fmaf(hi, wr.w, gim.w);
    }

    __shared__ float4 s_re[256], s_im[256];
    s_re[t] = gre; s_im[t] = gim;
    __syncthreads();
    if (t < 32) {
        float4 r = s_re[t], i = s_im[t];
        #pragma unroll
        for (int s = 1; s < 8; ++s) {
            float4 rr = s_re[s * 32 + t], ii = s_im[s * 32 + t];
            r.x += rr.x; r.y += rr.y; r.z += rr.z; r.w += rr.w;
            i.x += ii.x; i.y += ii.y; i.z += ii.z; i.w += ii.w;
        }
        float4* pr = (float4*)(part_re + (size_t)(slice * 128 + k) * 128);
        float4* pi = (float4*)(part_im + (size_t)(slice * 128 + k) * 128);
        pr[t] = r;
        pi[t] = i;
    }
}

__global__ __launch_bounds__(128) void rate_kernel(
    const float* __restrict__ part_re,
    const float* __restrict__ part_im,
    float* __restrict__ out)
{
    const int k = blockIdx.x;    // 0..127
    const int c = threadIdx.x;   // 0..127

    float gr = 0.f, gi = 0.f;
    #pragma unroll
    for (int s = 0; s < 8; ++s) {
        gr += part_re[(s * 128 + k) * 128 + c];
        gi += part_im[(s * 128 + k) * 128 + c];
    }
    float mag = sqrtf(gr * gr + gi * gi);

    __shared__ float s_sig;
    __shared__ float s_w[2];
    if (c == k) s_sig = mag;

    float v = mag;
    #pragma unroll
    for (int off = 32; off > 0; off >>= 1) v += __shfl_xor(v, off);
    if ((c & 63) == 0) s_w[c >> 6] = v;
    __syncthreads();

    if (c == 0) {
        float total  = s_w[0] + s_w[1];
        float interf = total - s_sig;
        float R      = s_sig / (interf + 1e-11f);   // N0 = 10^(-80/10)/1000
        atomicAdd(out, -R * 1e6f);
    }
}

extern "C" void kernel_launch(void* const* d_in, const int* in_sizes, int n_in,
                              void* d_out, int out_size, void* d_ws, size_t ws_size,
                              hipStream_t stream) {
    const float* W_v      = (const float*)d_in[0];
    const float* A_real   = (const float*)d_in[1];
    const float* A_imag   = (const float*)d_in[2];
    const float* h_d_real = (const float*)d_in[3];
    const float* h_d_imag = (const float*)d_in[4];
    float* out  = (float*)d_out;

    float* h_re    = (float*)d_ws;          // 131072 floats
    float* h_im    = h_re + KM_ROWS;        // 131072 floats
    float* part_re = h_im + KM_ROWS;        // 8*128*128 = 131072 floats
    float* part_im = part_re + 8 * 128 * 128;

    hipMemsetAsync(d_out, 0, sizeof(float), stream);

    compute_h_kernel<<<2048, 256, 0, stream>>>(A_real, A_imag, W_v,
                                               h_d_real, h_d_imag, h_re, h_im);
    gemm_partial_kernel<<<1024, 256, 0, stream>>>(h_re, h_im, W_v, part_re, part_im);
    rate_kernel<<<128, 128, 0, stream>>>(part_re, part_im, out);
}